// Round 1
// baseline (17.977 us; speedup 1.0000x reference)
//
#include <hip/hip_runtime.h>
#include <math.h>

#define NROWS 100000
#define DDIM 4
#define MCENT 256
#define EENS 10

// NORM_CONST = 1/((2*pi)^(D/2) * sigma^D) = 1/((2*pi)^2 * 1e-4)
#define NORM_CONST_F 253.30295910584444f
// -0.5/sigma^2 * log2(e) = -50 * 1.4426950408889634
#define EXP2_SCALE (-72.13475204444817f)

__global__ __launch_bounds__(256) void TAU_25503515803936_kernel(
    const float* __restrict__ x,                   // N x 4
    const float* __restrict__ ensemble_probs,      // N x 10
    const float* __restrict__ ensemble_norm_probs, // N x 1
    const float* __restrict__ weights,             // 10
    const float* __restrict__ centers,             // 256 x 4
    const float* __restrict__ coefficients,        // 256
    float* __restrict__ out)                       // [0,N): ensemble, [N,2N): net_out
{
    __shared__ float4 s_cent[MCENT];
    __shared__ float  s_wc[MCENT];
    __shared__ float  s_w[EENS];
    __shared__ float  s_red[4];

    const int t = threadIdx.x;
    const int lane = t & 63;
    const int wid  = t >> 6;

    // ---- stage centers (float4) + coefficients; compute mean via block reduce ----
    s_cent[t] = ((const float4*)centers)[t];
    float c = coefficients[t];
    if (t < EENS) s_w[t] = weights[t];

    float ws = c;
    #pragma unroll
    for (int off = 32; off > 0; off >>= 1)
        ws += __shfl_down(ws, off, 64);
    if (lane == 0) s_red[wid] = ws;
    __syncthreads();

    const float mean = (s_red[0] + s_red[1] + s_red[2] + s_red[3]) * (1.0f / 256.0f);
    s_wc[t] = c - mean;
    __syncthreads();

    const int i = blockIdx.x * 256 + t;
    if (i >= NROWS) return;

    // ---- ensemble: probs[i,:] . w  +  norm_probs[i] * (1 - sum(w)) ----
    float wsum = 0.0f;
    #pragma unroll
    for (int e = 0; e < EENS; ++e) wsum += s_w[e];
    const float wnorm = 1.0f - wsum;

    const float2* pr = (const float2*)(ensemble_probs + (size_t)i * EENS);
    float ens = ensemble_norm_probs[i] * wnorm;
    #pragma unroll
    for (int e2 = 0; e2 < EENS / 2; ++e2) {
        float2 p = pr[e2];
        ens = fmaf(p.x, s_w[2 * e2 + 0], ens);
        ens = fmaf(p.y, s_w[2 * e2 + 1], ens);
    }

    // ---- net_out: sum over 256 RBF centers ----
    const float4 xv = ((const float4*)x)[i];
    float acc = 0.0f;
    #pragma unroll 4
    for (int m = 0; m < MCENT; ++m) {
        const float4 cm = s_cent[m];
        const float dx = xv.x - cm.x;
        const float dy = xv.y - cm.y;
        const float dz = xv.z - cm.z;
        const float dw = xv.w - cm.w;
        float d2 = dx * dx;
        d2 = fmaf(dy, dy, d2);
        d2 = fmaf(dz, dz, d2);
        d2 = fmaf(dw, dw, d2);
        const float ev = __builtin_amdgcn_exp2f(d2 * EXP2_SCALE);
        acc = fmaf(s_wc[m], ev, acc);
    }

    out[i] = ens;
    out[NROWS + i] = acc * NORM_CONST_F;
}

extern "C" void kernel_launch(void* const* d_in, const int* in_sizes, int n_in,
                              void* d_out, int out_size, void* d_ws, size_t ws_size,
                              hipStream_t stream) {
    const float* x        = (const float*)d_in[0];
    const float* eprobs   = (const float*)d_in[1];
    const float* enorm    = (const float*)d_in[2];
    const float* weights  = (const float*)d_in[3];
    const float* centers  = (const float*)d_in[4];
    const float* coeffs   = (const float*)d_in[5];
    float* out = (float*)d_out;

    const int blocks = (NROWS + 255) / 256;  // 391
    TAU_25503515803936_kernel<<<blocks, 256, 0, stream>>>(
        x, eprobs, enorm, weights, centers, coeffs, out);
}

// Round 2
// 17.795 us; speedup vs baseline: 1.0102x; 1.0102x over previous
//
#include <hip/hip_runtime.h>
#include <math.h>

#define NROWS 100000
#define MCENT 256
#define EENS 10

// NORM_CONST = 1/((2*pi)^2 * sigma^4), sigma=0.1
#define NORM_CONST_F 253.30295910584444f
// -0.5/sigma^2 * log2(e) = -50 * 1.4426950408889634
#define EXP2_SCALE (-72.13475204444817f)

// d_ws layout: float4 G[256]  (G = -2*EXP2_SCALE*c)          bytes [0, 4096)
//              float2 AWC[256] (a = EXP2_SCALE*|c|^2, wc)     bytes [4096, 6144)

__global__ __launch_bounds__(256) void prep_kernel(
    const float* __restrict__ centers,       // 256 x 4
    const float* __restrict__ coefficients,  // 256
    float* __restrict__ ws)
{
    __shared__ float s_red[4];
    const int t = threadIdx.x;
    const int lane = t & 63, wid = t >> 6;

    float c = coefficients[t];
    float s = c;
    #pragma unroll
    for (int off = 32; off > 0; off >>= 1) s += __shfl_down(s, off, 64);
    if (lane == 0) s_red[wid] = s;
    __syncthreads();
    const float mean = (s_red[0] + s_red[1] + s_red[2] + s_red[3]) * (1.0f / 256.0f);

    const float4 cv = ((const float4*)centers)[t];
    float4 g;
    g.x = -2.0f * EXP2_SCALE * cv.x;
    g.y = -2.0f * EXP2_SCALE * cv.y;
    g.z = -2.0f * EXP2_SCALE * cv.z;
    g.w = -2.0f * EXP2_SCALE * cv.w;
    const float a = EXP2_SCALE * (cv.x * cv.x + cv.y * cv.y + cv.z * cv.z + cv.w * cv.w);

    ((float4*)ws)[t] = g;
    float2* awc = (float2*)(ws + 4 * MCENT);
    awc[t] = make_float2(a, c - mean);
}

__global__ __launch_bounds__(256) void main_kernel(
    const float* __restrict__ x,                   // N x 4
    const float* __restrict__ ensemble_probs,      // N x 10
    const float* __restrict__ ensemble_norm_probs, // N x 1
    const float* __restrict__ weights,             // 10
    const float* __restrict__ ws,
    float* __restrict__ out)                       // [0,N) ensemble, [N,2N) net_out
{
    __shared__ float s_part[4][64];
    const int t = threadIdx.x;
    const int lane = t & 63;
    const int wid = __builtin_amdgcn_readfirstlane(t >> 6);  // force SGPR -> scalar loads

    const int r = blockIdx.x * 64 + lane;
    const int rc = (r < NROWS) ? r : (NROWS - 1);

    const float4 xv = ((const float4*)x)[rc];
    const float h = EXP2_SCALE * (xv.x * xv.x + xv.y * xv.y + xv.z * xv.z + xv.w * xv.w);

    const float4* __restrict__ Gc = (const float4*)ws + wid * 64;
    const float2* __restrict__ Ac = (const float2*)(ws + 4 * MCENT) + wid * 64;

    float acc = 0.0f;
    #pragma unroll 8
    for (int k = 0; k < 64; ++k) {
        const float4 g = Gc[k];    // wave-uniform -> s_load_dwordx4
        const float2 aw = Ac[k];   // wave-uniform -> s_load_dwordx2
        float arg = h + aw.x;
        arg = fmaf(g.x, xv.x, arg);
        arg = fmaf(g.y, xv.y, arg);
        arg = fmaf(g.z, xv.z, arg);
        arg = fmaf(g.w, xv.w, arg);
        acc = fmaf(aw.y, __builtin_amdgcn_exp2f(arg), acc);
    }
    s_part[wid][lane] = acc;
    __syncthreads();

    if (wid == 0) {
        if (r < NROWS) {
            const float v = s_part[0][lane] + s_part[1][lane] +
                            s_part[2][lane] + s_part[3][lane];
            out[NROWS + r] = v * NORM_CONST_F;
        }
    } else if (wid == 1) {
        if (r < NROWS) {
            float wv[EENS];
            float wsum = 0.0f;
            #pragma unroll
            for (int e = 0; e < EENS; ++e) { wv[e] = weights[e]; wsum += wv[e]; }
            float ens = ensemble_norm_probs[r] * (1.0f - wsum);
            const float2* pr = (const float2*)(ensemble_probs + (size_t)r * EENS);
            #pragma unroll
            for (int e2 = 0; e2 < EENS / 2; ++e2) {
                const float2 p = pr[e2];
                ens = fmaf(p.x, wv[2 * e2 + 0], ens);
                ens = fmaf(p.y, wv[2 * e2 + 1], ens);
            }
            out[r] = ens;
        }
    }
}

extern "C" void kernel_launch(void* const* d_in, const int* in_sizes, int n_in,
                              void* d_out, int out_size, void* d_ws, size_t ws_size,
                              hipStream_t stream) {
    const float* x       = (const float*)d_in[0];
    const float* eprobs  = (const float*)d_in[1];
    const float* enorm   = (const float*)d_in[2];
    const float* weights = (const float*)d_in[3];
    const float* centers = (const float*)d_in[4];
    const float* coeffs  = (const float*)d_in[5];
    float* out = (float*)d_out;
    float* ws  = (float*)d_ws;

    prep_kernel<<<1, 256, 0, stream>>>(centers, coeffs, ws);

    const int blocks = (NROWS + 63) / 64;  // 1563
    main_kernel<<<blocks, 256, 0, stream>>>(x, eprobs, enorm, weights, ws, out);
}

// Round 3
// 15.346 us; speedup vs baseline: 1.1715x; 1.1596x over previous
//
#include <hip/hip_runtime.h>
#include <math.h>

#define NROWS 100000
#define MCENT 256
#define EENS 10

// NORM_CONST = 1/((2*pi)^2 * sigma^4), sigma=0.1
#define NORM_CONST_F 253.30295910584444f
// -0.5/sigma^2 * log2(e) = -50 * 1.4426950408889634
#define EXP2_SCALE (-72.13475204444817f)

__global__ __launch_bounds__(256) void fused_kernel(
    const float* __restrict__ x,                   // N x 4
    const float* __restrict__ ensemble_probs,      // N x 10
    const float* __restrict__ ensemble_norm_probs, // N x 1
    const float* __restrict__ weights,             // 10
    const float* __restrict__ centers,             // 256 x 4
    const float* __restrict__ coefficients,        // 256
    float* __restrict__ out)                       // [0,N) ensemble, [N,2N) net_out
{
    __shared__ float s_p1[4][64];
    __shared__ float s_p2[4][64];

    const int t = threadIdx.x;
    const int lane = t & 63;
    const int wid = __builtin_amdgcn_readfirstlane(t >> 6);  // SGPR -> scalar loads

    const int r = blockIdx.x * 64 + lane;
    const int rc = (r < NROWS) ? r : (NROWS - 1);

    const float4 xv = ((const float4*)x)[rc];

    // each wave owns a 64-center chunk; addresses wave-uniform -> s_load
    const float4* __restrict__ C = (const float4*)centers + wid * 64;
    const float*  __restrict__ K = coefficients + wid * 64;

    // net = sum(coef*e) - mean * sum(e)
    float a1_0 = 0.f, a1_1 = 0.f;  // sum coef*e (two chains for ILP)
    float a2_0 = 0.f, a2_1 = 0.f;  // sum e

    #pragma unroll 8
    for (int k = 0; k < 64; k += 2) {
        {
            const float4 c = C[k];
            const float cf = K[k];
            const float dx = xv.x - c.x, dy = xv.y - c.y,
                        dz = xv.z - c.z, dw = xv.w - c.w;
            float d2 = dx * dx;
            d2 = fmaf(dy, dy, d2);
            d2 = fmaf(dz, dz, d2);
            d2 = fmaf(dw, dw, d2);
            const float e = __builtin_amdgcn_exp2f(d2 * EXP2_SCALE);
            a1_0 = fmaf(cf, e, a1_0);
            a2_0 += e;
        }
        {
            const float4 c = C[k + 1];
            const float cf = K[k + 1];
            const float dx = xv.x - c.x, dy = xv.y - c.y,
                        dz = xv.z - c.z, dw = xv.w - c.w;
            float d2 = dx * dx;
            d2 = fmaf(dy, dy, d2);
            d2 = fmaf(dz, dz, d2);
            d2 = fmaf(dw, dw, d2);
            const float e = __builtin_amdgcn_exp2f(d2 * EXP2_SCALE);
            a1_1 = fmaf(cf, e, a1_1);
            a2_1 += e;
        }
    }

    s_p1[wid][lane] = a1_0 + a1_1;
    s_p2[wid][lane] = a2_0 + a2_1;
    __syncthreads();

    if (wid == 0) {
        // mean of coefficients: 64 lanes x float4 = 256 values, shuffle reduce
        const float4 cf4 = ((const float4*)coefficients)[lane];
        float s = (cf4.x + cf4.y) + (cf4.z + cf4.w);
        #pragma unroll
        for (int off = 32; off > 0; off >>= 1) s += __shfl_down(s, off, 64);
        const float mean = __builtin_amdgcn_readfirstlane(s) * (1.0f / 256.0f);

        if (r < NROWS) {
            const float P1 = (s_p1[0][lane] + s_p1[1][lane]) +
                             (s_p1[2][lane] + s_p1[3][lane]);
            const float P2 = (s_p2[0][lane] + s_p2[1][lane]) +
                             (s_p2[2][lane] + s_p2[3][lane]);
            out[NROWS + r] = (P1 - mean * P2) * NORM_CONST_F;
        }
    } else if (wid == 1) {
        if (r < NROWS) {
            float wv[EENS];
            float wsum = 0.0f;
            #pragma unroll
            for (int e = 0; e < EENS; ++e) { wv[e] = weights[e]; wsum += wv[e]; }
            float ens = ensemble_norm_probs[r] * (1.0f - wsum);
            const float2* pr = (const float2*)(ensemble_probs + (size_t)r * EENS);
            #pragma unroll
            for (int e2 = 0; e2 < EENS / 2; ++e2) {
                const float2 p = pr[e2];
                ens = fmaf(p.x, wv[2 * e2 + 0], ens);
                ens = fmaf(p.y, wv[2 * e2 + 1], ens);
            }
            out[r] = ens;
        }
    }
}

extern "C" void kernel_launch(void* const* d_in, const int* in_sizes, int n_in,
                              void* d_out, int out_size, void* d_ws, size_t ws_size,
                              hipStream_t stream) {
    const float* x       = (const float*)d_in[0];
    const float* eprobs  = (const float*)d_in[1];
    const float* enorm   = (const float*)d_in[2];
    const float* weights = (const float*)d_in[3];
    const float* centers = (const float*)d_in[4];
    const float* coeffs  = (const float*)d_in[5];
    float* out = (float*)d_out;

    const int blocks = (NROWS + 63) / 64;  // 1563
    fused_kernel<<<blocks, 256, 0, stream>>>(
        x, eprobs, enorm, weights, centers, coeffs, out);
}